// Round 6
// baseline (166.127 us; speedup 1.0000x reference)
//
#include <hip/hip_runtime.h>

#define B_TOT 65536
#define R 12
#define L 16
#define NB 16
#define NEG_MIN -3.402823466e38f

// ws layout (float index):
//   [0,32)   v[j]  (kw2 . qb2)
//   [32]     c     (qb2 . kb2)
//   [40,52)  pmask (as int: bit l set if freq_mask[r][l] != 0)
//   [64,96)  sorted breakpoints t[32]
//   [96, 96+33*72) interval table: row m (72 floats, 288 B)
//   [2472, 2472+1024) L1 weight MFMA fragments as shorts:
//        frag fr (=term*2+tile) : 64 lanes x short8; lane=kb*16+jl holds
//        Wterm[q(tile,jl)][kb*8..+7], q = (jl>>2)*8 + tile*4 + (jl&3)
//   term1 weights: k<11 -> wh_k, k==11 -> b_hi, else 0
//   term2 weights: k<11 -> wl_k, k==11 -> b_lo, 12<=k<23 -> wh_{k-12}, else 0
//   (input row for BOTH terms: [hi0..hi10, 1.0, lo0..lo10, 0])
#define WS_V   0
#define WS_C   32
#define WS_PM  40
#define WS_BP  64
#define WS_TAB 96
#define TROW   72
#define WS_WF  2472

// per-wave s_in region: 4 batches x 16 rows x 24 shorts + 8 pad shorts
#define WROWS (4 * 16 * 24 + 8)

typedef __attribute__((ext_vector_type(8))) short short8;
typedef __attribute__((ext_vector_type(4))) float f32x4;

static __device__ __forceinline__ short f2bf(float f) {
    uint32_t u = __float_as_uint(f);
    uint32_t r = u + 0x7FFFu + ((u >> 16) & 1u);  // round-to-nearest-even
    return (short)(r >> 16);
}

// HW packed f32->bf16 (RNE), 1 instruction for 2 elements.
static __device__ __forceinline__ unsigned cvt_pk_bf16(float a, float b) {
    unsigned d;
    asm("v_cvt_pk_bf16_f32 %0, %1, %2" : "=v"(d) : "v"(a), "v"(b));
    return d;
}

__global__ __launch_bounds__(256) void nfh_pre(
    const float* __restrict__ qw1, const float* __restrict__ qb1,
    const float* __restrict__ qw2, const float* __restrict__ qb2,
    const float* __restrict__ kw2, const float* __restrict__ kb2,
    const float* __restrict__ kw1, const float* __restrict__ kb1,
    const int*   __restrict__ fmask,
    float* __restrict__ ws)
{
    __shared__ float sM[1024];
    __shared__ float su[32];
    __shared__ float sw1[32], sb1[32], sbp[32], sbq[32];
    const int t = threadIdx.x;

    if (t < 32) { sw1[t] = qw1[t]; sb1[t] = qb1[t]; }
    for (int e = t; e < 1024; e += 256) {
        const int i = e >> 5, j = e & 31;
        float acc = 0.f;
        for (int h = 0; h < 64; ++h) acc = fmaf(qw2[i * 64 + h], kw2[j * 64 + h], acc);
        sM[e] = acc;
    }
    if (t < 32) {
        float au = 0.f, av = 0.f;
        for (int h = 0; h < 64; ++h) {
            au = fmaf(qw2[t * 64 + h], kb2[h], au);
            av = fmaf(kw2[t * 64 + h], qb2[h], av);
        }
        su[t] = au;
        ws[WS_V + t] = av;
        const float w = qw1[t];
        sbp[t] = (w != 0.f) ? (-qb1[t] / w) : 3.0e30f;
    }
    if (t == 64) {
        float acc = 0.f;
        for (int h = 0; h < 64; ++h) acc = fmaf(qb2[h], kb2[h], acc);
        ws[WS_C] = acc;
    }
    if (t < 12) {
        int pm = 0;
        for (int l = 0; l < 16; ++l) if (fmask[t * 16 + l] != 0) pm |= (1 << l);
        ((int*)ws)[WS_PM + t] = pm;
    }
    __syncthreads();
    // Parallel stable rank-sort of the 32 breakpoints (bit-identical to a
    // stable insertion sort on this NaN-free array).
    if (t < 32) {
        const float key = sbp[t];
        int rank = 0;
        #pragma unroll
        for (int i = 0; i < 32; ++i) {
            const float vi = sbp[i];
            rank += (vi < key || (vi == key && i < t)) ? 1 : 0;
        }
        sbq[rank] = key;
    }
    __syncthreads();
    if (t < 32) ws[WS_BP + t] = sbq[t];

    for (int task = t; task < 33 * 32 + 33; task += 256) {
        const int m = (task < 33 * 32) ? (task >> 5) : (task - 33 * 32);
        const float xi = (m == 0) ? sbq[0] - 1.f
                       : ((m == 32) ? sbq[31] + 1.f
                                    : sbq[m - 1] + 0.5f * (sbq[m] - sbq[m - 1]));
        if (task < 33 * 32) {
            const int j = task & 31;
            float A = 0.f, Bv = 0.f;
            for (int i = 0; i < 32; ++i) {
                if (fmaf(sw1[i], xi, sb1[i]) > 0.f) {
                    A  = fmaf(sw1[i], sM[i * 32 + j], A);
                    Bv = fmaf(sb1[i], sM[i * 32 + j], Bv);
                }
            }
            ws[WS_TAB + m * TROW + j] = A;
            ws[WS_TAB + m * TROW + 36 + j] = Bv;
        } else {
            float Au = 0.f, Bu = 0.f;
            for (int i = 0; i < 32; ++i) {
                if (fmaf(sw1[i], xi, sb1[i]) > 0.f) {
                    Au = fmaf(sw1[i], su[i], Au);
                    Bu = fmaf(sb1[i], su[i], Bu);
                }
            }
            ws[WS_TAB + m * TROW + 32] = Au;
            ws[WS_TAB + m * TROW + 36 + 32] = Bu;
        }
    }

    // ---- L1 weight MFMA fragments (hi/lo split), 4 frags x 64 lanes ----
    // Both terms consume the SAME input row [hi0..hi10, 1.0, lo0..lo10, 0]:
    //   term1: wh (slots 0..10) + b_hi (slot 11)
    //   term2: wl (slots 0..10) + b_lo (slot 11) + wh (slots 12..22)
    {
        const int fr = t >> 6;            // 0:t1T0 1:t1T1 2:t2T0 3:t2T1
        const int li = t & 63;
        const int jl = li & 15, kb = li >> 4;
        const int T = fr & 1, term = fr >> 1;
        const int q = ((jl >> 2) << 3) + (T << 2) + (jl & 3);
        short* wsp = (short*)(ws + WS_WF);
        #pragma unroll
        for (int e = 0; e < 8; ++e) {
            const int k = kb * 8 + e;
            float w = 0.f;
            if (term == 0) {
                if (k < 11)       w = kw1[k * 32 + q];
                else if (k == 11) w = kb1[q];
            } else {
                if (k < 11)       { const float a = kw1[k * 32 + q];
                                    w = a - __uint_as_float(((uint32_t)(uint16_t)f2bf(a)) << 16); }
                else if (k == 11) { const float b = kb1[q];
                                    w = b - __uint_as_float(((uint32_t)(uint16_t)f2bf(b)) << 16); }
                else if (k < 23)  w = kw1[(k - 12) * 32 + q];
            }
            wsp[(fr * 64 + li) * 8 + e] = f2bf(w);
        }
    }
}

// 256-thread, barrier-free, LDS = s_in only (12.4 KB -> wave-cap occupancy).
// All producer->consumer flows for wave w's batches are intra-wave:
//   P1 (bb=t>>4, l=t&15) -> one 24-short s_in row (per-wave padded region)
//   P2a (bb=t>>4, r=t&15) -> xq/k/tc kept in REGISTERS, shfl'd in P3
//   P3 wave w, batches w*4..w*4+3: ONE ds_read feeds all 4 L1 MFMAs;
//   B-frag rebuilt in-register from the L1-resident interval table.
__global__ __launch_bounds__(256, 8) void nfh_main(
    const float* __restrict__ rss,   // [B,R]
    const float* __restrict__ feat,  // [B,L,F]
    const float* __restrict__ pos,   // [B,L,3]
    const float* __restrict__ prev,  // [B,3]
    const float* __restrict__ gw1, const float* __restrict__ gb1,
    const float* __restrict__ gw2, const float* __restrict__ gb2,
    const float* __restrict__ sigma_p,
    const float* __restrict__ ws,
    float* __restrict__ out)
{
    // s_in row (24 shorts): [hi(in0..10), 1.0, lo(in0..10), +0.0]
    __shared__ short s_in[4 * WROWS];   // 12,352 B

    const int t = threadIdx.x;
    const int lane = t & 63;
    const int wv = t >> 6;
    const int lg = lane >> 4;
    const int b0 = blockIdx.x * NB;
    const float sigma = sigma_p[0];
    const float inv2s2 = 1.f / (2.f * sigma * sigma);

    // L1 weight frags + v-frag + c (uniform across blocks -> L2 broadcast)
    const short* wsp = (const short*)(ws + WS_WF);
    const short8 wf0 = *(const short8*)(wsp + (0 * 64 + lane) * 8);
    const short8 wf1 = *(const short8*)(wsp + (1 * 64 + lane) * 8);
    const short8 wf2 = *(const short8*)(wsp + (2 * 64 + lane) * 8);
    const short8 wf3 = *(const short8*)(wsp + (3 * 64 + lane) * 8);
    const f32x4 v0 = *(const f32x4*)(ws + WS_V + lg * 8);
    const f32x4 v1 = *(const f32x4*)(ws + WS_V + lg * 8 + 4);
    const float cconst = ws[WS_C];

    // per-wave pad zero (read only via 0-weight K-slots; keep bits finite)
    if (lane < 8) s_in[wv * WROWS + 4 * 16 * 24 + lane] = 0;

    float my_dq;   // c - dsq/(2s^2) for (bb=t>>4, l=t&15)
    // ---------- P1: (bb1 = t>>4, l1 = t&15): load, hi/lo split -> LDS row ----------
    {
        const int bb1 = t >> 4, l1 = t & 15;
        const int b = b0 + bb1;
        float in[12];
        const float4* f4 = (const float4*)(feat + ((size_t)b * (L * 8) + l1 * 8));
        const float4 fa = f4[0], fb = f4[1];
        in[0] = fa.x; in[1] = fa.y; in[2] = fa.z; in[3] = fa.w;
        in[4] = fb.x; in[5] = fb.y; in[6] = fb.z; in[7] = fb.w;
        const float* pp = pos + ((size_t)b * (L * 3) + l1 * 3);
        in[8] = pp[0]; in[9] = pp[1]; in[10] = pp[2];
        in[11] = 1.0f;

        float dsq = 0.f;
        #pragma unroll
        for (int m = 0; m < 3; ++m) {
            const float d = prev[b * 3 + m] - in[8 + m];
            dsq = fmaf(d, d, dsq);
        }
        my_dq = cconst - dsq * inv2s2;

        unsigned hp[6], lp[6];
        #pragma unroll
        for (int p = 0; p < 6; ++p) {
            const float a = in[2 * p], c = in[2 * p + 1];
            const unsigned h = cvt_pk_bf16(a, c);
            hp[p] = h;
            const float h0 = __uint_as_float(h << 16);
            const float h1 = __uint_as_float(h & 0xFFFF0000u);
            lp[p] = cvt_pk_bf16(a - h0, c - h1);  // p==5: (lo10, 1.0-1.0 = +0.0)
        }

        uint4* rowp = (uint4*)&s_in[wv * WROWS + ((bb1 & 3) * 16 + l1) * 24];
        rowp[0] = make_uint4(hp[0], hp[1], hp[2], hp[3]);
        rowp[1] = make_uint4(hp[4], hp[5], lp[0], lp[1]);
        rowp[2] = make_uint4(lp[2], lp[3], lp[4], lp[5]);
    }

    // ---------- P2a: (bb2 = t>>4, r2 = t&15): gate -> iw; xq/k/tc in regs ----------
    float my_xq = 0.f;
    {
        const int bb2 = t >> 4;
        const int r2 = t & 15;
        if (r2 < R) {
            const int b = b0 + bb2;
            const float x = rss[(size_t)b * R + r2];
            float z = gb2[0];
            #pragma unroll
            for (int i = 0; i < 16; ++i) {
                const float h = fmaxf(fmaf(x, gw1[i], gb1[i]), 0.f);
                z = fmaf(h, gw2[i], z);
            }
            const float gate = 1.f / (1.f + __expf(-z));
            const float iw = (x > 0.5f) ? gate : 0.f;
            out[(size_t)B_TOT * R * L + (size_t)b * R + r2] = iw;
            my_xq = x * iw;
        }
    }
    int my_k = 0;
    #pragma unroll
    for (int m = 0; m < 32; ++m) my_k += (my_xq > ws[WS_BP + m]) ? 1 : 0;
    const float* myrow = ws + WS_TAB + my_k * TROW;
    const float my_tc = fmaf(my_xq, myrow[32], myrow[68]);

    // Intra-wave LDS visibility: this wave's ds_writes complete.
    asm volatile("s_waitcnt lgkmcnt(0)" ::: "memory");

    // ---------- P3: wave wv, batches wv*4..wv*4+3 ----------
    {
        const int r = lane & 15;
        const int pm = (r < R) ? ((const int*)ws)[WS_PM + r] : 0;
        const int j0 = lg * 8;

        #pragma unroll 1
        for (int i = 0; i < 4; ++i) {
            const int bb = wv * 4 + i;
            const int src = i * 16 + r;
            const float xq_s = __shfl(my_xq, src);
            const int   k_s  = __shfl(my_k,  src);
            const float tc_s = __shfl(my_tc, src);
            const float dq_s = __shfl(my_dq, src);

            // single frag read serves both hi/lo terms (weight slots permuted)
            const short8 i1 = *(const short8*)(&s_in[wv * WROWS + (i * 16 + r) * 24] + j0);

            f32x4 d0 = {0.f, 0.f, 0.f, 0.f};
            f32x4 d1 = {0.f, 0.f, 0.f, 0.f};
            d0 = __builtin_amdgcn_mfma_f32_16x16x32_bf16(wf0, i1, d0, 0, 0, 0);
            d0 = __builtin_amdgcn_mfma_f32_16x16x32_bf16(wf2, i1, d0, 0, 0, 0);
            d1 = __builtin_amdgcn_mfma_f32_16x16x32_bf16(wf1, i1, d1, 0, 0, 0);
            d1 = __builtin_amdgcn_mfma_f32_16x16x32_bf16(wf3, i1, d1, 0, 0, 0);

            float vbp = 0.f;
            #pragma unroll
            for (int j = 0; j < 4; ++j) {
                d0[j] = fmaxf(d0[j], 0.f);
                vbp = fmaf(v0[j], d0[j], vbp);
            }
            #pragma unroll
            for (int j = 0; j < 4; ++j) {
                d1[j] = fmaxf(d1[j], 0.f);
                vbp = fmaf(v1[j], d1[j], vbp);
            }
            vbp += __shfl_xor(vbp, 16);
            vbp += __shfl_xor(vbp, 32);
            const float vbl = vbp + dq_s;  // valid at every lane for l=lane&15

            uint4 afp;
            afp.x = cvt_pk_bf16(d0[0], d0[1]);
            afp.y = cvt_pk_bf16(d0[2], d0[3]);
            afp.z = cvt_pk_bf16(d1[0], d1[1]);
            afp.w = cvt_pk_bf16(d1[2], d1[3]);
            const short8 af = *(const short8*)&afp;

            // B-frag rebuilt in-register from the interval table (L1-resident).
            // Columns r>=12 are garbage-but-finite; they only affect discarded
            // D columns.
            const float* rowt = ws + WS_TAB + k_s * TROW;
            const float4 a0 = *(const float4*)(rowt + j0);
            const float4 a1 = *(const float4*)(rowt + j0 + 4);
            const float4 c0 = *(const float4*)(rowt + 36 + j0);
            const float4 c1 = *(const float4*)(rowt + 36 + j0 + 4);
            uint4 bfp;
            bfp.x = cvt_pk_bf16(fmaf(xq_s, a0.x, c0.x), fmaf(xq_s, a0.y, c0.y));
            bfp.y = cvt_pk_bf16(fmaf(xq_s, a0.z, c0.z), fmaf(xq_s, a0.w, c0.w));
            bfp.z = cvt_pk_bf16(fmaf(xq_s, a1.x, c1.x), fmaf(xq_s, a1.y, c1.y));
            bfp.w = cvt_pk_bf16(fmaf(xq_s, a1.z, c1.z), fmaf(xq_s, a1.w, c1.w));
            const short8 bf = *(const short8*)&bfp;

            f32x4 acc = {0.f, 0.f, 0.f, 0.f};
            acc = __builtin_amdgcn_mfma_f32_16x16x32_bf16(af, bf, acc, 0, 0, 0);

            float sc[4];
            #pragma unroll
            for (int j = 0; j < 4; ++j) {
                const float vbj = __shfl(vbl, lg * 4 + j);
                sc[j] = acc[j] + tc_s + vbj;
                if (!((pm >> (lg * 4 + j)) & 1)) sc[j] = NEG_MIN;
            }
            float mx = fmaxf(fmaxf(sc[0], sc[1]), fmaxf(sc[2], sc[3]));
            mx = fmaxf(mx, __shfl_xor(mx, 16));
            mx = fmaxf(mx, __shfl_xor(mx, 32));
            float sum = 0.f;
            #pragma unroll
            for (int j = 0; j < 4; ++j) { sc[j] = __expf(sc[j] - mx); sum += sc[j]; }
            sum += __shfl_xor(sum, 16);
            sum += __shfl_xor(sum, 32);
            const float inv = 1.f / sum;

            if (r < R) {
                float4* op = (float4*)(out + ((size_t)(b0 + bb) * R + r) * L + lg * 4);
                *op = make_float4(sc[0] * inv, sc[1] * inv, sc[2] * inv, sc[3] * inv);
            }
        }
    }
}

extern "C" void kernel_launch(void* const* d_in, const int* in_sizes, int n_in,
                              void* d_out, int out_size, void* d_ws, size_t ws_size,
                              hipStream_t stream) {
    const float* rss   = (const float*)d_in[0];
    const float* feat  = (const float*)d_in[1];
    const float* pos   = (const float*)d_in[2];
    const float* prev  = (const float*)d_in[3];
    const int*   fmask = (const int*)d_in[4];
    const float* gw1   = (const float*)d_in[5];
    const float* gb1   = (const float*)d_in[6];
    const float* gw2   = (const float*)d_in[7];
    const float* gb2   = (const float*)d_in[8];
    const float* qw1   = (const float*)d_in[9];
    const float* qb1   = (const float*)d_in[10];
    const float* qw2   = (const float*)d_in[11];
    const float* qb2   = (const float*)d_in[12];
    const float* kw1   = (const float*)d_in[13];
    const float* kb1   = (const float*)d_in[14];
    const float* kw2   = (const float*)d_in[15];
    const float* kb2   = (const float*)d_in[16];
    const float* sigma = (const float*)d_in[17];
    float* out = (float*)d_out;
    float* ws  = (float*)d_ws;

    nfh_pre<<<1, 256, 0, stream>>>(qw1, qb1, qw2, qb2, kw2, kb2, kw1, kb1, fmask, ws);
    nfh_main<<<B_TOT / NB, 256, 0, stream>>>(
        rss, feat, pos, prev,
        gw1, gb1, gw2, gb2,
        sigma, ws, out);
}

// Round 7
// 164.778 us; speedup vs baseline: 1.0082x; 1.0082x over previous
//
#include <hip/hip_runtime.h>

#define B_TOT 65536
#define R 12
#define L 16
#define NB 32
#define NEG_MIN -3.402823466e38f

// ws layout (float index):
//   [0,32)   v[j]  (kw2 . qb2)
//   [32]     c     (qb2 . kb2)
//   [40,52)  pmask (as int: bit l set if freq_mask[r][l] != 0)
//   [64,96)  sorted breakpoints t[32]
//   [96, 96+33*72) interval table: row m (72 floats, 288 B)
//   [2472, 2472+1024) L1 weight MFMA fragments as shorts:
//        frag fr (=term*2+tile) : 64 lanes x short8; lane=kb*16+jl holds
//        Wterm[q(tile,jl)][kb*8..+7], q = (jl>>2)*8 + tile*4 + (jl&3)
//   term1 weights: k<11 -> wh_k, k==11 -> b_hi, else 0
//   term2 weights: k<11 -> wl_k, k==11 -> b_lo, 12<=k<23 -> wh_{k-12}, else 0
//   (input row for BOTH terms: [hi0..hi10, 1.0, lo0..lo10, 0])
#define WS_V   0
#define WS_C   32
#define WS_PM  40
#define WS_BP  64
#define WS_TAB 96
#define TROW   72
#define WS_WF  2472

// per-wave s_in region: 8 batches x 16 rows x 24 shorts + 8 pad shorts
#define WROWS (8 * 16 * 24 + 8)

typedef __attribute__((ext_vector_type(8))) short short8;
typedef __attribute__((ext_vector_type(4))) float f32x4;

static __device__ __forceinline__ short f2bf(float f) {
    uint32_t u = __float_as_uint(f);
    uint32_t r = u + 0x7FFFu + ((u >> 16) & 1u);  // round-to-nearest-even
    return (short)(r >> 16);
}

// HW packed f32->bf16 (RNE), 1 instruction for 2 elements.
static __device__ __forceinline__ unsigned cvt_pk_bf16(float a, float b) {
    unsigned d;
    asm("v_cvt_pk_bf16_f32 %0, %1, %2" : "=v"(d) : "v"(a), "v"(b));
    return d;
}

__global__ __launch_bounds__(256) void nfh_pre(
    const float* __restrict__ qw1, const float* __restrict__ qb1,
    const float* __restrict__ qw2, const float* __restrict__ qb2,
    const float* __restrict__ kw2, const float* __restrict__ kb2,
    const float* __restrict__ kw1, const float* __restrict__ kb1,
    const int*   __restrict__ fmask,
    float* __restrict__ ws)
{
    __shared__ float sM[1024];
    __shared__ float su[32];
    __shared__ float sw1[32], sb1[32], sbp[32], sbq[32];
    const int t = threadIdx.x;

    if (t < 32) { sw1[t] = qw1[t]; sb1[t] = qb1[t]; }
    for (int e = t; e < 1024; e += 256) {
        const int i = e >> 5, j = e & 31;
        float acc = 0.f;
        for (int h = 0; h < 64; ++h) acc = fmaf(qw2[i * 64 + h], kw2[j * 64 + h], acc);
        sM[e] = acc;
    }
    if (t < 32) {
        float au = 0.f, av = 0.f;
        for (int h = 0; h < 64; ++h) {
            au = fmaf(qw2[t * 64 + h], kb2[h], au);
            av = fmaf(kw2[t * 64 + h], qb2[h], av);
        }
        su[t] = au;
        ws[WS_V + t] = av;
        const float w = qw1[t];
        sbp[t] = (w != 0.f) ? (-qb1[t] / w) : 3.0e30f;
    }
    if (t == 64) {
        float acc = 0.f;
        for (int h = 0; h < 64; ++h) acc = fmaf(qb2[h], kb2[h], acc);
        ws[WS_C] = acc;
    }
    if (t < 12) {
        int pm = 0;
        for (int l = 0; l < 16; ++l) if (fmask[t * 16 + l] != 0) pm |= (1 << l);
        ((int*)ws)[WS_PM + t] = pm;
    }
    __syncthreads();
    // Parallel stable rank-sort of the 32 breakpoints (bit-identical to a
    // stable insertion sort on this NaN-free array).
    if (t < 32) {
        const float key = sbp[t];
        int rank = 0;
        #pragma unroll
        for (int i = 0; i < 32; ++i) {
            const float vi = sbp[i];
            rank += (vi < key || (vi == key && i < t)) ? 1 : 0;
        }
        sbq[rank] = key;
    }
    __syncthreads();
    if (t < 32) ws[WS_BP + t] = sbq[t];

    for (int task = t; task < 33 * 32 + 33; task += 256) {
        const int m = (task < 33 * 32) ? (task >> 5) : (task - 33 * 32);
        const float xi = (m == 0) ? sbq[0] - 1.f
                       : ((m == 32) ? sbq[31] + 1.f
                                    : sbq[m - 1] + 0.5f * (sbq[m] - sbq[m - 1]));
        if (task < 33 * 32) {
            const int j = task & 31;
            float A = 0.f, Bv = 0.f;
            for (int i = 0; i < 32; ++i) {
                if (fmaf(sw1[i], xi, sb1[i]) > 0.f) {
                    A  = fmaf(sw1[i], sM[i * 32 + j], A);
                    Bv = fmaf(sb1[i], sM[i * 32 + j], Bv);
                }
            }
            ws[WS_TAB + m * TROW + j] = A;
            ws[WS_TAB + m * TROW + 36 + j] = Bv;
        } else {
            float Au = 0.f, Bu = 0.f;
            for (int i = 0; i < 32; ++i) {
                if (fmaf(sw1[i], xi, sb1[i]) > 0.f) {
                    Au = fmaf(sw1[i], su[i], Au);
                    Bu = fmaf(sb1[i], su[i], Bu);
                }
            }
            ws[WS_TAB + m * TROW + 32] = Au;
            ws[WS_TAB + m * TROW + 36 + 32] = Bu;
        }
    }

    // ---- L1 weight MFMA fragments (hi/lo split), 4 frags x 64 lanes ----
    // Both terms consume the SAME input row [hi0..hi10, 1.0, lo0..lo10, 0]:
    //   term1: wh (slots 0..10) + b_hi (slot 11)
    //   term2: wl (slots 0..10) + b_lo (slot 11) + wh (slots 12..22)
    {
        const int fr = t >> 6;            // 0:t1T0 1:t1T1 2:t2T0 3:t2T1
        const int li = t & 63;
        const int jl = li & 15, kb = li >> 4;
        const int T = fr & 1, term = fr >> 1;
        const int q = ((jl >> 2) << 3) + (T << 2) + (jl & 3);
        short* wsp = (short*)(ws + WS_WF);
        #pragma unroll
        for (int e = 0; e < 8; ++e) {
            const int k = kb * 8 + e;
            float w = 0.f;
            if (term == 0) {
                if (k < 11)       w = kw1[k * 32 + q];
                else if (k == 11) w = kb1[q];
            } else {
                if (k < 11)       { const float a = kw1[k * 32 + q];
                                    w = a - __uint_as_float(((uint32_t)(uint16_t)f2bf(a)) << 16); }
                else if (k == 11) { const float b = kb1[q];
                                    w = b - __uint_as_float(((uint32_t)(uint16_t)f2bf(b)) << 16); }
                else if (k < 23)  w = kw1[(k - 12) * 32 + q];
            }
            wsp[(fr * 64 + li) * 8 + e] = f2bf(w);
        }
    }
}

// 256-thread, barrier-free, NB=32: wave wv owns batches wv*8..wv*8+7.
// Each lane runs P1/P2a TWICE (p=0: bb=wv*8+(lane>>4), p=1: +4), with all
// global loads issued in one up-front burst. P3 runs 8 iterations with
// unroll 2 so the scattered table-load chains of consecutive iterations
// overlap. No min-occupancy bound: spend VGPRs on ILP (the 64-reg bet
// never raised measured residency, r4-r6).
__global__ __launch_bounds__(256) void nfh_main(
    const float* __restrict__ rss,   // [B,R]
    const float* __restrict__ feat,  // [B,L,F]
    const float* __restrict__ pos,   // [B,L,3]
    const float* __restrict__ prev,  // [B,3]
    const float* __restrict__ gw1, const float* __restrict__ gb1,
    const float* __restrict__ gw2, const float* __restrict__ gb2,
    const float* __restrict__ sigma_p,
    const float* __restrict__ ws,
    float* __restrict__ out)
{
    // s_in row (24 shorts): [hi(in0..10), 1.0, lo(in0..10), +0.0]
    __shared__ short s_in[4 * WROWS];   // 24,640 B

    const int t = threadIdx.x;
    const int lane = t & 63;
    const int wv = t >> 6;
    const int lg = lane >> 4;
    const int b0 = blockIdx.x * NB;
    const int bw = b0 + wv * 8;          // wave's first batch
    const float sigma = sigma_p[0];
    const float inv2s2 = 1.f / (2.f * sigma * sigma);

    // L1 weight frags + v-frag + c (uniform across blocks -> L2 broadcast)
    const short* wsp = (const short*)(ws + WS_WF);
    const short8 wf0 = *(const short8*)(wsp + (0 * 64 + lane) * 8);
    const short8 wf1 = *(const short8*)(wsp + (1 * 64 + lane) * 8);
    const short8 wf2 = *(const short8*)(wsp + (2 * 64 + lane) * 8);
    const short8 wf3 = *(const short8*)(wsp + (3 * 64 + lane) * 8);
    const f32x4 v0 = *(const f32x4*)(ws + WS_V + lg * 8);
    const f32x4 v1 = *(const f32x4*)(ws + WS_V + lg * 8 + 4);
    const float cconst = ws[WS_C];

    // per-wave pad zero (read only via 0-weight K-slots; keep bits finite)
    if (lane < 8) s_in[wv * WROWS + 8 * 16 * 24 + lane] = 0;

    const int l1 = lane & 15;
    const int bl = lane >> 4;            // 0..3
    const int b_p0 = bw + bl, b_p1 = bw + 4 + bl;

    // ---------- up-front global load burst (both p) ----------
    const float4* f40 = (const float4*)(feat + ((size_t)b_p0 * (L * 8) + l1 * 8));
    const float4* f41 = (const float4*)(feat + ((size_t)b_p1 * (L * 8) + l1 * 8));
    const float4 fa0 = f40[0], fb0 = f40[1];
    const float4 fa1 = f41[0], fb1 = f41[1];
    const float* pp0 = pos + ((size_t)b_p0 * (L * 3) + l1 * 3);
    const float* pp1 = pos + ((size_t)b_p1 * (L * 3) + l1 * 3);
    const float px0 = pp0[0], py0 = pp0[1], pz0 = pp0[2];
    const float px1 = pp1[0], py1 = pp1[1], pz1 = pp1[2];
    const float qx0 = prev[b_p0 * 3], qy0 = prev[b_p0 * 3 + 1], qz0 = prev[b_p0 * 3 + 2];
    const float qx1 = prev[b_p1 * 3], qy1 = prev[b_p1 * 3 + 1], qz1 = prev[b_p1 * 3 + 2];
    float x0 = 0.f, x1 = 0.f;
    if (l1 < R) {
        x0 = rss[(size_t)b_p0 * R + l1];
        x1 = rss[(size_t)b_p1 * R + l1];
    }

    // ---------- P1 (both p): hi/lo split -> LDS row ----------
    float my_dq0, my_dq1;
    {
        float in[12];
        in[0] = fa0.x; in[1] = fa0.y; in[2] = fa0.z; in[3] = fa0.w;
        in[4] = fb0.x; in[5] = fb0.y; in[6] = fb0.z; in[7] = fb0.w;
        in[8] = px0; in[9] = py0; in[10] = pz0; in[11] = 1.0f;
        float dsq = 0.f;
        dsq = fmaf(qx0 - px0, qx0 - px0, dsq);
        dsq = fmaf(qy0 - py0, qy0 - py0, dsq);
        dsq = fmaf(qz0 - pz0, qz0 - pz0, dsq);
        my_dq0 = cconst - dsq * inv2s2;

        unsigned hp[6], lp[6];
        #pragma unroll
        for (int p = 0; p < 6; ++p) {
            const float a = in[2 * p], c = in[2 * p + 1];
            const unsigned h = cvt_pk_bf16(a, c);
            hp[p] = h;
            const float h0 = __uint_as_float(h << 16);
            const float h1 = __uint_as_float(h & 0xFFFF0000u);
            lp[p] = cvt_pk_bf16(a - h0, c - h1);
        }
        uint4* rowp = (uint4*)&s_in[wv * WROWS + (bl * 16 + l1) * 24];
        rowp[0] = make_uint4(hp[0], hp[1], hp[2], hp[3]);
        rowp[1] = make_uint4(hp[4], hp[5], lp[0], lp[1]);
        rowp[2] = make_uint4(lp[2], lp[3], lp[4], lp[5]);
    }
    {
        float in[12];
        in[0] = fa1.x; in[1] = fa1.y; in[2] = fa1.z; in[3] = fa1.w;
        in[4] = fb1.x; in[5] = fb1.y; in[6] = fb1.z; in[7] = fb1.w;
        in[8] = px1; in[9] = py1; in[10] = pz1; in[11] = 1.0f;
        float dsq = 0.f;
        dsq = fmaf(qx1 - px1, qx1 - px1, dsq);
        dsq = fmaf(qy1 - py1, qy1 - py1, dsq);
        dsq = fmaf(qz1 - pz1, qz1 - pz1, dsq);
        my_dq1 = cconst - dsq * inv2s2;

        unsigned hp[6], lp[6];
        #pragma unroll
        for (int p = 0; p < 6; ++p) {
            const float a = in[2 * p], c = in[2 * p + 1];
            const unsigned h = cvt_pk_bf16(a, c);
            hp[p] = h;
            const float h0 = __uint_as_float(h << 16);
            const float h1 = __uint_as_float(h & 0xFFFF0000u);
            lp[p] = cvt_pk_bf16(a - h0, c - h1);
        }
        uint4* rowp = (uint4*)&s_in[wv * WROWS + ((bl + 4) * 16 + l1) * 24];
        rowp[0] = make_uint4(hp[0], hp[1], hp[2], hp[3]);
        rowp[1] = make_uint4(hp[4], hp[5], lp[0], lp[1]);
        rowp[2] = make_uint4(lp[2], lp[3], lp[4], lp[5]);
    }

    // ---------- P2a (both p): gate -> iw; xq/k/tc in registers ----------
    float my_xq0 = 0.f, my_xq1 = 0.f;
    if (l1 < R) {
        float z0 = gb2[0], z1 = gb2[0];
        #pragma unroll
        for (int i = 0; i < 16; ++i) {
            const float w1 = gw1[i], bb1_ = gb1[i], w2 = gw2[i];
            z0 = fmaf(fmaxf(fmaf(x0, w1, bb1_), 0.f), w2, z0);
            z1 = fmaf(fmaxf(fmaf(x1, w1, bb1_), 0.f), w2, z1);
        }
        const float g0 = 1.f / (1.f + __expf(-z0));
        const float g1 = 1.f / (1.f + __expf(-z1));
        const float iw0 = (x0 > 0.5f) ? g0 : 0.f;
        const float iw1 = (x1 > 0.5f) ? g1 : 0.f;
        out[(size_t)B_TOT * R * L + (size_t)b_p0 * R + l1] = iw0;
        out[(size_t)B_TOT * R * L + (size_t)b_p1 * R + l1] = iw1;
        my_xq0 = x0 * iw0;
        my_xq1 = x1 * iw1;
    }
    int my_k0 = 0, my_k1 = 0;
    #pragma unroll
    for (int m = 0; m < 32; ++m) {
        const float bp = ws[WS_BP + m];
        my_k0 += (my_xq0 > bp) ? 1 : 0;
        my_k1 += (my_xq1 > bp) ? 1 : 0;
    }
    const float* myrow0 = ws + WS_TAB + my_k0 * TROW;
    const float* myrow1 = ws + WS_TAB + my_k1 * TROW;
    const float my_tc0 = fmaf(my_xq0, myrow0[32], myrow0[68]);
    const float my_tc1 = fmaf(my_xq1, myrow1[32], myrow1[68]);

    // Intra-wave LDS visibility: this wave's ds_writes complete.
    asm volatile("s_waitcnt lgkmcnt(0)" ::: "memory");

    // ---------- P3: wave wv, batches wv*8..wv*8+7 ----------
    {
        const int r = lane & 15;
        const int pm = (r < R) ? ((const int*)ws)[WS_PM + r] : 0;
        const int j0 = lg * 8;

        #pragma unroll 2
        for (int i = 0; i < 8; ++i) {
            const int src = ((i & 3) << 4) | r;
            const bool hi = (i >= 4);
            // select THEN shfl: 'hi' is wave-uniform, so the source lane's
            // selected value is exactly its own p=hi state.
            const float xq_s = __shfl(hi ? my_xq1 : my_xq0, src);
            const int   k_s  = __shfl(hi ? my_k1  : my_k0,  src);
            const float tc_s = __shfl(hi ? my_tc1 : my_tc0, src);
            const float dq_s = __shfl(hi ? my_dq1 : my_dq0, src);

            // single frag read serves both hi/lo terms (weight slots permuted)
            const short8 i1 = *(const short8*)(&s_in[wv * WROWS + (i * 16 + r) * 24] + j0);

            f32x4 d0 = {0.f, 0.f, 0.f, 0.f};
            f32x4 d1 = {0.f, 0.f, 0.f, 0.f};
            d0 = __builtin_amdgcn_mfma_f32_16x16x32_bf16(wf0, i1, d0, 0, 0, 0);
            d0 = __builtin_amdgcn_mfma_f32_16x16x32_bf16(wf2, i1, d0, 0, 0, 0);
            d1 = __builtin_amdgcn_mfma_f32_16x16x32_bf16(wf1, i1, d1, 0, 0, 0);
            d1 = __builtin_amdgcn_mfma_f32_16x16x32_bf16(wf3, i1, d1, 0, 0, 0);

            float vbp = 0.f;
            #pragma unroll
            for (int j = 0; j < 4; ++j) {
                d0[j] = fmaxf(d0[j], 0.f);
                vbp = fmaf(v0[j], d0[j], vbp);
            }
            #pragma unroll
            for (int j = 0; j < 4; ++j) {
                d1[j] = fmaxf(d1[j], 0.f);
                vbp = fmaf(v1[j], d1[j], vbp);
            }
            vbp += __shfl_xor(vbp, 16);
            vbp += __shfl_xor(vbp, 32);
            const float vbl = vbp + dq_s;  // valid at every lane for l=lane&15

            uint4 afp;
            afp.x = cvt_pk_bf16(d0[0], d0[1]);
            afp.y = cvt_pk_bf16(d0[2], d0[3]);
            afp.z = cvt_pk_bf16(d1[0], d1[1]);
            afp.w = cvt_pk_bf16(d1[2], d1[3]);
            const short8 af = *(const short8*)&afp;

            // B-frag rebuilt in-register from the interval table (L1-resident).
            // Columns r>=12 are garbage-but-finite; they only affect discarded
            // D columns.
            const float* rowt = ws + WS_TAB + k_s * TROW;
            const float4 a0 = *(const float4*)(rowt + j0);
            const float4 a1 = *(const float4*)(rowt + j0 + 4);
            const float4 c0 = *(const float4*)(rowt + 36 + j0);
            const float4 c1 = *(const float4*)(rowt + 36 + j0 + 4);
            uint4 bfp;
            bfp.x = cvt_pk_bf16(fmaf(xq_s, a0.x, c0.x), fmaf(xq_s, a0.y, c0.y));
            bfp.y = cvt_pk_bf16(fmaf(xq_s, a0.z, c0.z), fmaf(xq_s, a0.w, c0.w));
            bfp.z = cvt_pk_bf16(fmaf(xq_s, a1.x, c1.x), fmaf(xq_s, a1.y, c1.y));
            bfp.w = cvt_pk_bf16(fmaf(xq_s, a1.z, c1.z), fmaf(xq_s, a1.w, c1.w));
            const short8 bf = *(const short8*)&bfp;

            f32x4 acc = {0.f, 0.f, 0.f, 0.f};
            acc = __builtin_amdgcn_mfma_f32_16x16x32_bf16(af, bf, acc, 0, 0, 0);

            float sc[4];
            #pragma unroll
            for (int j = 0; j < 4; ++j) {
                const float vbj = __shfl(vbl, lg * 4 + j);
                sc[j] = acc[j] + tc_s + vbj;
                if (!((pm >> (lg * 4 + j)) & 1)) sc[j] = NEG_MIN;
            }
            float mx = fmaxf(fmaxf(sc[0], sc[1]), fmaxf(sc[2], sc[3]));
            mx = fmaxf(mx, __shfl_xor(mx, 16));
            mx = fmaxf(mx, __shfl_xor(mx, 32));
            float sum = 0.f;
            #pragma unroll
            for (int j = 0; j < 4; ++j) { sc[j] = __expf(sc[j] - mx); sum += sc[j]; }
            sum += __shfl_xor(sum, 16);
            sum += __shfl_xor(sum, 32);
            const float inv = 1.f / sum;

            if (r < R) {
                float4* op = (float4*)(out + ((size_t)(bw + i) * R + r) * L + lg * 4);
                *op = make_float4(sc[0] * inv, sc[1] * inv, sc[2] * inv, sc[3] * inv);
            }
        }
    }
}

extern "C" void kernel_launch(void* const* d_in, const int* in_sizes, int n_in,
                              void* d_out, int out_size, void* d_ws, size_t ws_size,
                              hipStream_t stream) {
    const float* rss   = (const float*)d_in[0];
    const float* feat  = (const float*)d_in[1];
    const float* pos   = (const float*)d_in[2];
    const float* prev  = (const float*)d_in[3];
    const int*   fmask = (const int*)d_in[4];
    const float* gw1   = (const float*)d_in[5];
    const float* gb1   = (const float*)d_in[6];
    const float* gw2   = (const float*)d_in[7];
    const float* gb2   = (const float*)d_in[8];
    const float* qw1   = (const float*)d_in[9];
    const float* qb1   = (const float*)d_in[10];
    const float* qw2   = (const float*)d_in[11];
    const float* qb2   = (const float*)d_in[12];
    const float* kw1   = (const float*)d_in[13];
    const float* kb1   = (const float*)d_in[14];
    const float* kw2   = (const float*)d_in[15];
    const float* kb2   = (const float*)d_in[16];
    const float* sigma = (const float*)d_in[17];
    float* out = (float*)d_out;
    float* ws  = (float*)d_ws;

    nfh_pre<<<1, 256, 0, stream>>>(qw1, qb1, qw2, qb2, kw2, kb2, kw1, kb1, fmask, ws);
    nfh_main<<<B_TOT / NB, 256, 0, stream>>>(
        rss, feat, pos, prev,
        gw1, gb1, gw2, gb2,
        sigma, ws, out);
}